// Round 2
// baseline (1734.782 us; speedup 1.0000x reference)
//
#include <hip/hip_runtime.h>

// Block_21380347200224: LN1 -> 3D spectral filter (9x11x9, rfft last axis) -> LN2 ->
// low-rank MLP (900->450->1800 gelu ->450->900) -> +x residual.
// B=64, N=891, C=900, tokens M=57024.
//
// R5: GEMM re-geometried to the proven 256x256 / BK=64 / 512-thread / 8-wave tile
// (learn_hip m230/m201 class). R4 evidence: bank conflicts -> 0 but time flat;
// MfmaUtil 8.4 / VALUBusy 9.4 / HBM 34% => stall-bound at the 2-barrier-per-32K
// structure. Now each iteration = 64 MFMA/wave between one {vmcnt(8); s_barrier}
// and one {s_barrier} -- 4x MFMA per stall point, 4x fewer blocks. Counted vmcnt
// kept (8 loads/tile, 2 tiles in flight). 3-bit XOR swizzle (chunk ^= row&7) on
// the 128B LDS rows, applied global-side (rule #21) + on the ds_read.
// K dims padded to multiples of 64: yn stride 960, t2 stride 1856.

typedef unsigned short u16;
typedef __bf16 bf16x8 __attribute__((ext_vector_type(8)));
typedef float f32x4 __attribute__((ext_vector_type(4)));

#define LN_EPS 1e-5f
#define CH 16   // channels per spectral block: LDS = 2*5*99*16*4 = 63360 B

// ---------------- twiddle tables (folded to immediates after unroll) ----------------
constexpr float KC9[9] = {
  1.0f, 0.766044443118978f, 0.17364817766693041f, -0.4999999999999998f,
  -0.9396926207859083f, -0.9396926207859084f, -0.5000000000000004f,
  0.17364817766692997f, 0.7660444431189778f };
constexpr float KS9[9] = {
  0.0f, 0.6427876096865393f, 0.984807753012208f, 0.8660254037844387f,
  0.3420201433256689f, -0.34202014332566866f, -0.8660254037844385f,
  -0.9848077530122081f, -0.6427876096865396f };
constexpr float KC11[11] = {
  1.0f, 0.8412535328311812f, 0.41541501300188644f, -0.14231483827328512f,
  -0.654860733945285f, -0.9594929736144974f, -0.9594929736144974f,
  -0.6548607339452852f, -0.14231483827328543f, 0.4154150130018863f,
  0.8412535328311811f };
constexpr float KS11[11] = {
  0.0f, 0.5406408174555976f, 0.9096319953545183f, 0.9898214418809327f,
  0.7557495743542583f, 0.2817325568414297f, -0.2817325568414296f,
  -0.7557495743542582f, -0.9898214418809327f, -0.9096319953545184f,
  -0.5406408174555979f };

__device__ __forceinline__ u16 f2bf(float f) {           // RNE float->bf16
  unsigned int u = __float_as_uint(f);
  return (u16)((u + 0x7fffu + ((u >> 16) & 1u)) >> 16);
}
// tanh-form gelu: max |dev| from exact erf-gelu ~3e-4 (threshold 0.131). ~8 VALU ops.
__device__ __forceinline__ float gelu_f(float v) {
  float t = 0.7978845608028654f * v * (1.f + 0.044715f * v * v);
  float e = __expf(2.f * t);
  float th = 1.f - 2.f * __builtin_amdgcn_rcpf(e + 1.f);
  return 0.5f * v * (1.f + th);
}

// ---------------- weight conversion ----------------
__global__ __launch_bounds__(256) void k_cvt(const float* __restrict__ s, u16* __restrict__ d,
                                             int rows, int sc, int dc,
                                             const float* __restrict__ gamma) {
  int i = blockIdx.x * 256 + threadIdx.x;
  if (i >= rows * dc) return;
  int r = i / dc, c = i % dc;
  u16 o = 0;
  if (c < sc) {
    float v = s[(size_t)r * sc + c];
    if (gamma) v *= gamma[c];
    o = f2bf(v);
  }
  d[i] = o;
}

__global__ __launch_bounds__(256) void k_bias1(const float* __restrict__ u1w,
                                               const float* __restrict__ b2,
                                               float* __restrict__ out) {
  int r = blockIdx.x * 256 + threadIdx.x;
  if (r < 450) {
    float s = 0.f;
    for (int c = 0; c < 900; c++) s += u1w[r * 900 + c] * b2[c];
    out[r] = s;  // beta2 folded through u1
  }
}

// ---------------- LN1 stats: wave per token ----------------
__global__ __launch_bounds__(256) void k_stats1(const float* __restrict__ x,
                                                float2* __restrict__ stats) {
  int tok = blockIdx.x * 4 + (threadIdx.x >> 6);
  int l = threadIdx.x & 63;
  const float* row = x + (size_t)tok * 900;
  float s1 = 0.f, s2 = 0.f;
#pragma unroll
  for (int j = 0; j < 15; j++) {
    int c = l + j * 64;
    if (c < 900) { float a = row[c]; s1 += a; s2 += a * a; }
  }
#pragma unroll
  for (int off = 32; off; off >>= 1) { s1 += __shfl_xor(s1, off, 64); s2 += __shfl_xor(s2, off, 64); }
  if (l == 0) {
    float m = s1 * (1.f / 900.f);
    float var = s2 * (1.f / 900.f) - m * m;
    stats[tok] = make_float2(m, rsqrtf(var + LN_EPS));
  }
}

// ---------------- fused 3D spectral filter ----------------
__global__ __launch_bounds__(256) void k_spectral(const float* __restrict__ x,
                                                  const float2* __restrict__ stats,
                                                  const float* __restrict__ g1,
                                                  const float* __restrict__ b1,
                                                  const float* __restrict__ cw,
                                                  float* __restrict__ y) {
  __shared__ float sre[5 * 99 * CH];
  __shared__ float sim[5 * 99 * CH];
  int b = blockIdx.x / 57, cc = blockIdx.x % 57;
  int c0 = cc * CH;
  int t = threadIdx.x;
  const float* xb = x + (size_t)b * 801900;
  const float2* st = stats + (size_t)b * 891;

  // pass 1: LN1 + d-rfft (9 -> 5)
  for (int col = t; col < 99 * CH; col += 256) {
    int pos = col / CH, c = col % CH;
    int cg = c0 + c; bool ok = cg < 900;
    float g = ok ? g1[cg] : 0.f, be = ok ? b1[cg] : 0.f;
    float yv[9];
#pragma unroll
    for (int d = 0; d < 9; d++) {
      float a = ok ? xb[(size_t)(pos * 9 + d) * 900 + cg] : 0.f;
      float2 s = st[pos * 9 + d];
      yv[d] = (a - s.x) * s.y * g + be;
    }
#pragma unroll
    for (int kd = 0; kd < 5; kd++) {
      float re = 0.f, im = 0.f;
#pragma unroll
      for (int d = 0; d < 9; d++) { int j = (kd * d) % 9; re += yv[d] * KC9[j]; im -= yv[d] * KS9[j]; }
      sre[(kd * 99 + pos) * CH + c] = re;
      sim[(kd * 99 + pos) * CH + c] = im;
    }
  }
  __syncthreads();

  // pass 2: forward 11-pt DFT over w
  for (int col = t; col < 5 * 9 * CH; col += 256) {
    int kd = col / (9 * CH), r = col % (9 * CH), h = r / CH, c = r % CH;
    int base = (kd * 99 + h * 11) * CH + c;
    float xr[11], xi[11];
#pragma unroll
    for (int w = 0; w < 11; w++) { xr[w] = sre[base + w * CH]; xi[w] = sim[base + w * CH]; }
#pragma unroll
    for (int k = 0; k < 11; k++) {
      float yr = 0.f, yi = 0.f;
#pragma unroll
      for (int w = 0; w < 11; w++) {
        int j = (k * w) % 11; float cf = KC11[j], sf = KS11[j];
        yr += xr[w] * cf + xi[w] * sf;
        yi += xi[w] * cf - xr[w] * sf;
      }
      sre[base + k * CH] = yr; sim[base + k * CH] = yi;
    }
  }
  __syncthreads();

  // pass 3: 9-pt h-DFT * weight * 9-pt h-iDFT
  for (int col = t; col < 5 * 11 * CH; col += 256) {
    int kd = col / (11 * CH), r = col % (11 * CH), kw = r / CH, c = r % CH;
    int cg = c0 + c;
    int base = (kd * 99 + kw) * CH + c;
    float xr[9], xi[9];
#pragma unroll
    for (int h = 0; h < 9; h++) { xr[h] = sre[base + h * 11 * CH]; xi[h] = sim[base + h * 11 * CH]; }
    float zr[9], zi[9];
#pragma unroll
    for (int k = 0; k < 9; k++) {
      float yr = 0.f, yi = 0.f;
#pragma unroll
      for (int h = 0; h < 9; h++) {
        int j = (k * h) % 9; float cf = KC9[j], sf = KS9[j];
        yr += xr[h] * cf + xi[h] * sf;
        yi += xi[h] * cf - xr[h] * sf;
      }
      float wr = 0.f, wi = 0.f;
      if (cg < 900) {
        size_t widx = ((size_t)((k * 11 + kw) * 5 + kd) * 900 + cg) * 2;
        wr = cw[widx]; wi = cw[widx + 1];
      }
      zr[k] = yr * wr - yi * wi;
      zi[k] = yr * wi + yi * wr;
    }
#pragma unroll
    for (int h = 0; h < 9; h++) {
      float orr = 0.f, oi = 0.f;
#pragma unroll
      for (int k = 0; k < 9; k++) {
        int j = (k * h) % 9; float cf = KC9[j], sf = KS9[j];
        orr += zr[k] * cf - zi[k] * sf;
        oi  += zi[k] * cf + zr[k] * sf;
      }
      sre[base + h * 11 * CH] = orr; sim[base + h * 11 * CH] = oi;
    }
  }
  __syncthreads();

  // pass 4: inverse 11-pt DFT over w
  for (int col = t; col < 5 * 9 * CH; col += 256) {
    int kd = col / (9 * CH), r = col % (9 * CH), h = r / CH, c = r % CH;
    int base = (kd * 99 + h * 11) * CH + c;
    float xr[11], xi[11];
#pragma unroll
    for (int w = 0; w < 11; w++) { xr[w] = sre[base + w * CH]; xi[w] = sim[base + w * CH]; }
#pragma unroll
    for (int k = 0; k < 11; k++) {
      float yr = 0.f, yi = 0.f;
#pragma unroll
      for (int w = 0; w < 11; w++) {
        int j = (k * w) % 11; float cf = KC11[j], sf = KS11[j];
        yr += xr[w] * cf - xi[w] * sf;
        yi += xi[w] * cf + xr[w] * sf;
      }
      sre[base + k * CH] = yr; sim[base + k * CH] = yi;
    }
  }
  __syncthreads();

  // pass 5: d-irfft (5 -> 9), ortho scale, write y
  for (int col = t; col < 99 * CH; col += 256) {
    int pos = col / CH, c = col % CH;
    int cg = c0 + c;
    if (cg >= 900) continue;
    float Xr[5], Xi[5];
#pragma unroll
    for (int k = 0; k < 5; k++) { Xr[k] = sre[(k * 99 + pos) * CH + c]; Xi[k] = sim[(k * 99 + pos) * CH + c]; }
#pragma unroll
    for (int d = 0; d < 9; d++) {
      float acc = Xr[0];
#pragma unroll
      for (int k = 1; k < 5; k++) { int j = (k * d) % 9; acc += 2.f * (Xr[k] * KC9[j] - Xi[k] * KS9[j]); }
      y[((size_t)b * 891 + pos * 9 + d) * 900 + cg] = acc * (1.f / 891.f);
    }
  }
}

// ---------------- LN2 + bf16 emit (stride 960): wave per token ----------------
__global__ __launch_bounds__(256) void k_ln2(const float* __restrict__ y, u16* __restrict__ yn) {
  int tok = blockIdx.x * 4 + (threadIdx.x >> 6);
  int l = threadIdx.x & 63;
  const float* row = y + (size_t)tok * 900;
  float v[15];
  float s1 = 0.f, s2 = 0.f;
#pragma unroll
  for (int j = 0; j < 15; j++) {
    int c = l + j * 64;
    float a = (c < 900) ? row[c] : 0.f;
    v[j] = a; s1 += a; s2 += a * a;
  }
#pragma unroll
  for (int off = 32; off; off >>= 1) { s1 += __shfl_xor(s1, off, 64); s2 += __shfl_xor(s2, off, 64); }
  float m = s1 * (1.f / 900.f);
  float var = s2 * (1.f / 900.f) - m * m;
  float rs = rsqrtf(var + LN_EPS);
  u16* orow = yn + (size_t)tok * 960;
#pragma unroll
  for (int j = 0; j < 15; j++) {
    int c = l + j * 64;
    if (c < 900) orow[c] = f2bf((v[j] - m) * rs);
    else orow[c] = 0;   // pad to 960
  }
}

// ---------------- bf16 MFMA GEMM, C = A(MxK) . B(NxK)^T ----------------
// 256x256 tile, BK=64, 512 threads (8 waves, 2M x 4N), double-buffered LDS 128KB,
// counted vmcnt(8) pipeline, 3-bit XOR swizzle on 128B LDS rows.
typedef __attribute__((address_space(1))) void gvoid;
typedef __attribute__((address_space(3))) void svoid;

__device__ __forceinline__ void stage16(const u16* g, u16* lbase) {
  __builtin_amdgcn_global_load_lds((gvoid*)(void*)g, (svoid*)lbase, 16, 0, 0);
}

// stage one 256x64 A-tile + 256x64 B-tile: 8 global_load_lds per thread (4 A + 4 B).
// LDS dest linear (lane-consecutive 16B chunks); swizzle applied to the GLOBAL
// k-chunk: LDS chunk c of row r holds global chunk c ^ (r&7)  (rule #21).
__device__ __forceinline__ void stage_tile(const u16* __restrict__ A, const u16* __restrict__ B,
                                           int m0, int n0, int M, int N, int ldk, int k0,
                                           u16* As, u16* Bs, int t) {
#pragma unroll
  for (int j = 0; j < 4; j++) {
    int g = (j << 9) + t;                 // chunk id 0..2047
    int r = g >> 3;                       // row 0..255
    int cs = ((g & 7) ^ (r & 7)) << 3;    // swizzled k-offset in u16
    int gm = m0 + r; gm = gm < M ? gm : M - 1;
    stage16(A + (size_t)gm * ldk + k0 + cs, &As[g << 3]);
    int gn = n0 + r; gn = gn < N ? gn : N - 1;
    stage16(B + (size_t)gn * ldk + k0 + cs, &Bs[g << 3]);
  }
}

// EPI: 0 = bf16 store + bias (G1)   1 = bf16 store gelu(.+bias) (G2)
//      2 = bf16 store plain (G3)    3 = fp32 out = . + bias + x (G4)
template <int EPI>
__global__ __launch_bounds__(512, 2) void k_gemm(
    const u16* __restrict__ A, const u16* __restrict__ B,
    int M, int N, int Kt, int ldk, int NT,
    u16* __restrict__ Ob, int ldo, int Nstore,
    const float* __restrict__ bias,
    const float* __restrict__ Xres, float* __restrict__ Of) {
  __shared__ __align__(16) u16 As[2][256 * 64];
  __shared__ __align__(16) u16 Bs[2][256 * 64];
  int t = threadIdx.x, w = t >> 6, l = t & 63;
  int mt = blockIdx.x / NT, nt = blockIdx.x % NT;
  int m0 = mt << 8, n0 = nt << 8;
  int wm = (w >> 2) << 7;     // wave M-half: 0 / 128
  int wn = (w & 3) << 6;      // wave N-quarter: 0/64/128/192
  int fr = l & 15, fq = l >> 4;

  f32x4 acc[8][4];
  f32x4 zero = {0.f, 0.f, 0.f, 0.f};
#pragma unroll
  for (int i = 0; i < 8; i++)
#pragma unroll
    for (int j = 0; j < 4; j++) acc[i][j] = zero;

  // prologue: tiles 0 and 1 in flight (16 loads/thread)
  stage_tile(A, B, m0, n0, M, N, ldk, 0, As[0], Bs[0], t);
  if (Kt > 1) stage_tile(A, B, m0, n0, M, N, ldk, 64, As[1], Bs[1], t);

  for (int kt = 0; kt < Kt; ++kt) {
    // drain ONLY tile kt's 8 loads (tile kt+1's 8 stay in flight), then barrier.
    if (kt + 1 < Kt) asm volatile("s_waitcnt vmcnt(8)\n\ts_barrier" ::: "memory");
    else             asm volatile("s_waitcnt vmcnt(0)\n\ts_barrier" ::: "memory");

    const u16* as = As[kt & 1];
    const u16* bs = Bs[kt & 1];
#pragma unroll
    for (int ks = 0; ks < 2; ks++) {
      // read-side inverse swizzle: chunk = (ks*4+fq) ^ (row&7), row&7 == fr&7
      int csw = ((((ks << 2) | fq) ^ (fr & 7)) << 3);
      bf16x8 af[8], bfv[4];
#pragma unroll
      for (int i = 0; i < 8; i++) af[i] = *(const bf16x8*)&as[(wm + (i << 4) + fr) * 64 + csw];
#pragma unroll
      for (int j = 0; j < 4; j++) bfv[j] = *(const bf16x8*)&bs[(wn + (j << 4) + fr) * 64 + csw];
      __builtin_amdgcn_s_setprio(1);
#pragma unroll
      for (int i = 0; i < 8; i++)
#pragma unroll
        for (int j = 0; j < 4; j++)
          acc[i][j] = __builtin_amdgcn_mfma_f32_16x16x32_bf16(af[i], bfv[j], acc[i][j], 0, 0, 0);
      __builtin_amdgcn_s_setprio(0);
    }

    // all waves done reading buf[kt&1] before restaging into it
    asm volatile("s_barrier" ::: "memory");
    if (kt + 2 < Kt)
      stage_tile(A, B, m0, n0, M, N, ldk, (kt + 2) << 6, As[kt & 1], Bs[kt & 1], t);
  }

#pragma unroll
  for (int j = 0; j < 4; j++) {
    int gn = n0 + wn + (j << 4) + fr;
    float bv = 0.f;
    if (EPI != 2) bv = (gn < Nstore) ? bias[gn] : 0.f;
#pragma unroll
    for (int i = 0; i < 8; i++) {
#pragma unroll
      for (int r = 0; r < 4; r++) {
        int gm = m0 + wm + (i << 4) + (fq << 2) + r;
        if (gm < M) {
          float val = acc[i][j][r] + bv;
          if (EPI == 1) val = gelu_f(val);
          if (EPI == 3) {
            if (gn < Nstore) Of[(size_t)gm * Nstore + gn] = val + Xres[(size_t)gm * Nstore + gn];
          } else {
            if (gn < ldo) Ob[(size_t)gm * ldo + gn] = (gn < Nstore) ? f2bf(val) : (u16)0;
          }
        }
      }
    }
  }
}

// ---------------- launch ----------------
extern "C" void kernel_launch(void* const* d_in, const int* in_sizes, int n_in,
                              void* d_out, int out_size, void* d_ws, size_t ws_size,
                              hipStream_t stream) {
  const float* x   = (const float*)d_in[0];
  const float* cw  = (const float*)d_in[1];
  const float* g1  = (const float*)d_in[2];
  const float* b1  = (const float*)d_in[3];
  const float* g2  = (const float*)d_in[4];
  const float* b2  = (const float*)d_in[5];
  const float* u1w = (const float*)d_in[6];
  const float* v1w = (const float*)d_in[7];
  const float* v1b = (const float*)d_in[8];
  const float* u2w = (const float*)d_in[9];
  const float* v2w = (const float*)d_in[10];
  const float* v2b = (const float*)d_in[11];

  char* ws = (char*)d_ws;
  float* y   = (float*)ws;                       // 205,286,400 B (dead before t2 written)
  u16*   t2  = (u16*)ws;                         // 57024*1856*2 = 211,673,088 B (reuses y)
  u16*   t3  = (u16*)(ws + 211673088);           // 57024*512*2 = 58,392,576 B
  u16*   u1g = (u16*)(ws + 270065664);           // 450*960*2  = 864,000 B
  u16*   v1c = (u16*)(ws + 270929664);           // 1800*512*2 = 1,843,200 B
  u16*   u2c = (u16*)(ws + 272772864);           // 450*1856*2 = 1,670,400 B
  u16*   v2c = (u16*)(ws + 274443264);           // 900*512*2  = 921,600 B
  float* b1r = (float*)(ws + 275364864);         // 450*4

  u16*    yn    = (u16*)d_out;                       // 57024*960*2 = 109,486,080 B
  u16*    t1    = (u16*)((char*)d_out + 109486080);  // 57024*512*2 = 58,392,576 B
  float2* stats = (float2*)((char*)d_out + 167878656); // 456,192 B (< 205,286,400 total)
  float*  outF  = (float*)d_out;

  // weight prep (tiny)
  k_cvt<<<1688, 256, 0, stream>>>(u1w, u1g, 450, 900, 960, g2);
  k_cvt<<<3600, 256, 0, stream>>>(v1w, v1c, 1800, 450, 512, nullptr);
  k_cvt<<<3263, 256, 0, stream>>>(u2w, u2c, 450, 1800, 1856, nullptr);
  k_cvt<<<1800, 256, 0, stream>>>(v2w, v2c, 900, 450, 512, nullptr);
  k_bias1<<<2, 256, 0, stream>>>(u1w, b2, b1r);

  // spectral filter (fused)
  k_stats1<<<14256, 256, 0, stream>>>(x, stats);
  k_spectral<<<64 * 57, 256, 0, stream>>>(x, stats, g1, b1, cw, y);
  k_ln2<<<14256, 256, 0, stream>>>(y, yn);

  // MLP GEMMs: M=57024 -> 223 tiles of 256
  k_gemm<0><<<223 * 2, 512, 0, stream>>>(yn, u1g, 57024, 450,  15, 960,  2, t1, 512, 450, b1r, nullptr, nullptr);
  k_gemm<1><<<223 * 8, 512, 0, stream>>>(t1, v1c, 57024, 1800, 8,  512,  8, t2, 1856, 1800, v1b, nullptr, nullptr);
  k_gemm<2><<<223 * 2, 512, 0, stream>>>(t2, u2c, 57024, 450,  29, 1856, 2, t3, 512, 450, nullptr, nullptr, nullptr);
  k_gemm<3><<<223 * 4, 512, 0, stream>>>(t3, v2c, 57024, 900,  8,  512,  4, nullptr, 0, 900, v2b, x, outF);
}

// Round 3
// 1455.515 us; speedup vs baseline: 1.1919x; 1.1919x over previous
//
#include <hip/hip_runtime.h>

// Block_21380347200224: LN1 -> 3D spectral filter (9x11x9, rfft last axis) -> LN2 ->
// low-rank MLP (900->450->1800 gelu ->450->900) -> +x residual.
// B=64, N=891, C=900, tokens M=57024.
//
// R6: revert to R4's 128x128/BK=32/256-thread GEMM (R5's 256x256 tile = 1 block/CU,
// no latency cover -> regression) + XCD-chunked block mapping (T1, m204 bijective).
// R4 evidence: FETCH ~504 MB vs 58 MB unique A on G2 => ~8x cross-XCD A duplication;
// A-loads were HBM misses (~900cy) that the 1-iteration pipeline can't hide.
// Blocks are now enumerated mt-major and chunked per XCD so one XCD runs all
// N-tiles of an M-tile consecutively -> A L2-resident, vmcnt stall shrinks.
// Kept from R4: counted vmcnt(4) 2-stage pipeline, 2-bit XOR LDS swizzle
// (bank conflicts measured 0).

typedef unsigned short u16;
typedef __bf16 bf16x8 __attribute__((ext_vector_type(8)));
typedef float f32x4 __attribute__((ext_vector_type(4)));

#define LN_EPS 1e-5f
#define CH 16   // channels per spectral block: LDS = 2*5*99*16*4 = 63360 B

// ---------------- twiddle tables (folded to immediates after unroll) ----------------
constexpr float KC9[9] = {
  1.0f, 0.766044443118978f, 0.17364817766693041f, -0.4999999999999998f,
  -0.9396926207859083f, -0.9396926207859084f, -0.5000000000000004f,
  0.17364817766692997f, 0.7660444431189778f };
constexpr float KS9[9] = {
  0.0f, 0.6427876096865393f, 0.984807753012208f, 0.8660254037844387f,
  0.3420201433256689f, -0.34202014332566866f, -0.8660254037844385f,
  -0.9848077530122081f, -0.6427876096865396f };
constexpr float KC11[11] = {
  1.0f, 0.8412535328311812f, 0.41541501300188644f, -0.14231483827328512f,
  -0.654860733945285f, -0.9594929736144974f, -0.9594929736144974f,
  -0.6548607339452852f, -0.14231483827328543f, 0.4154150130018863f,
  0.8412535328311811f };
constexpr float KS11[11] = {
  0.0f, 0.5406408174555976f, 0.9096319953545183f, 0.9898214418809327f,
  0.7557495743542583f, 0.2817325568414297f, -0.2817325568414296f,
  -0.7557495743542582f, -0.9898214418809327f, -0.9096319953545184f,
  -0.5406408174555979f };

__device__ __forceinline__ u16 f2bf(float f) {           // RNE float->bf16
  unsigned int u = __float_as_uint(f);
  return (u16)((u + 0x7fffu + ((u >> 16) & 1u)) >> 16);
}
// tanh-form gelu: max |dev| from exact erf-gelu ~3e-4 (threshold 0.131). ~8 VALU ops.
__device__ __forceinline__ float gelu_f(float v) {
  float t = 0.7978845608028654f * v * (1.f + 0.044715f * v * v);
  float e = __expf(2.f * t);
  float th = 1.f - 2.f * __builtin_amdgcn_rcpf(e + 1.f);
  return 0.5f * v * (1.f + th);
}

// ---------------- weight conversion ----------------
__global__ __launch_bounds__(256) void k_cvt(const float* __restrict__ s, u16* __restrict__ d,
                                             int rows, int sc, int dc,
                                             const float* __restrict__ gamma) {
  int i = blockIdx.x * 256 + threadIdx.x;
  if (i >= rows * dc) return;
  int r = i / dc, c = i % dc;
  u16 o = 0;
  if (c < sc) {
    float v = s[(size_t)r * sc + c];
    if (gamma) v *= gamma[c];
    o = f2bf(v);
  }
  d[i] = o;
}

__global__ __launch_bounds__(256) void k_bias1(const float* __restrict__ u1w,
                                               const float* __restrict__ b2,
                                               float* __restrict__ out) {
  int r = blockIdx.x * 256 + threadIdx.x;
  if (r < 450) {
    float s = 0.f;
    for (int c = 0; c < 900; c++) s += u1w[r * 900 + c] * b2[c];
    out[r] = s;  // beta2 folded through u1
  }
}

// ---------------- LN1 stats: wave per token ----------------
__global__ __launch_bounds__(256) void k_stats1(const float* __restrict__ x,
                                                float2* __restrict__ stats) {
  int tok = blockIdx.x * 4 + (threadIdx.x >> 6);
  int l = threadIdx.x & 63;
  const float* row = x + (size_t)tok * 900;
  float s1 = 0.f, s2 = 0.f;
#pragma unroll
  for (int j = 0; j < 15; j++) {
    int c = l + j * 64;
    if (c < 900) { float a = row[c]; s1 += a; s2 += a * a; }
  }
#pragma unroll
  for (int off = 32; off; off >>= 1) { s1 += __shfl_xor(s1, off, 64); s2 += __shfl_xor(s2, off, 64); }
  if (l == 0) {
    float m = s1 * (1.f / 900.f);
    float var = s2 * (1.f / 900.f) - m * m;
    stats[tok] = make_float2(m, rsqrtf(var + LN_EPS));
  }
}

// ---------------- fused 3D spectral filter ----------------
__global__ __launch_bounds__(256) void k_spectral(const float* __restrict__ x,
                                                  const float2* __restrict__ stats,
                                                  const float* __restrict__ g1,
                                                  const float* __restrict__ b1,
                                                  const float* __restrict__ cw,
                                                  float* __restrict__ y) {
  __shared__ float sre[5 * 99 * CH];
  __shared__ float sim[5 * 99 * CH];
  int b = blockIdx.x / 57, cc = blockIdx.x % 57;
  int c0 = cc * CH;
  int t = threadIdx.x;
  const float* xb = x + (size_t)b * 801900;
  const float2* st = stats + (size_t)b * 891;

  // pass 1: LN1 + d-rfft (9 -> 5)
  for (int col = t; col < 99 * CH; col += 256) {
    int pos = col / CH, c = col % CH;
    int cg = c0 + c; bool ok = cg < 900;
    float g = ok ? g1[cg] : 0.f, be = ok ? b1[cg] : 0.f;
    float yv[9];
#pragma unroll
    for (int d = 0; d < 9; d++) {
      float a = ok ? xb[(size_t)(pos * 9 + d) * 900 + cg] : 0.f;
      float2 s = st[pos * 9 + d];
      yv[d] = (a - s.x) * s.y * g + be;
    }
#pragma unroll
    for (int kd = 0; kd < 5; kd++) {
      float re = 0.f, im = 0.f;
#pragma unroll
      for (int d = 0; d < 9; d++) { int j = (kd * d) % 9; re += yv[d] * KC9[j]; im -= yv[d] * KS9[j]; }
      sre[(kd * 99 + pos) * CH + c] = re;
      sim[(kd * 99 + pos) * CH + c] = im;
    }
  }
  __syncthreads();

  // pass 2: forward 11-pt DFT over w
  for (int col = t; col < 5 * 9 * CH; col += 256) {
    int kd = col / (9 * CH), r = col % (9 * CH), h = r / CH, c = r % CH;
    int base = (kd * 99 + h * 11) * CH + c;
    float xr[11], xi[11];
#pragma unroll
    for (int w = 0; w < 11; w++) { xr[w] = sre[base + w * CH]; xi[w] = sim[base + w * CH]; }
#pragma unroll
    for (int k = 0; k < 11; k++) {
      float yr = 0.f, yi = 0.f;
#pragma unroll
      for (int w = 0; w < 11; w++) {
        int j = (k * w) % 11; float cf = KC11[j], sf = KS11[j];
        yr += xr[w] * cf + xi[w] * sf;
        yi += xi[w] * cf - xr[w] * sf;
      }
      sre[base + k * CH] = yr; sim[base + k * CH] = yi;
    }
  }
  __syncthreads();

  // pass 3: 9-pt h-DFT * weight * 9-pt h-iDFT
  for (int col = t; col < 5 * 11 * CH; col += 256) {
    int kd = col / (11 * CH), r = col % (11 * CH), kw = r / CH, c = r % CH;
    int cg = c0 + c;
    int base = (kd * 99 + kw) * CH + c;
    float xr[9], xi[9];
#pragma unroll
    for (int h = 0; h < 9; h++) { xr[h] = sre[base + h * 11 * CH]; xi[h] = sim[base + h * 11 * CH]; }
    float zr[9], zi[9];
#pragma unroll
    for (int k = 0; k < 9; k++) {
      float yr = 0.f, yi = 0.f;
#pragma unroll
      for (int h = 0; h < 9; h++) {
        int j = (k * h) % 9; float cf = KC9[j], sf = KS9[j];
        yr += xr[h] * cf + xi[h] * sf;
        yi += xi[h] * cf - xr[h] * sf;
      }
      float wr = 0.f, wi = 0.f;
      if (cg < 900) {
        size_t widx = ((size_t)((k * 11 + kw) * 5 + kd) * 900 + cg) * 2;
        wr = cw[widx]; wi = cw[widx + 1];
      }
      zr[k] = yr * wr - yi * wi;
      zi[k] = yr * wi + yi * wr;
    }
#pragma unroll
    for (int h = 0; h < 9; h++) {
      float orr = 0.f, oi = 0.f;
#pragma unroll
      for (int k = 0; k < 9; k++) {
        int j = (k * h) % 9; float cf = KC9[j], sf = KS9[j];
        orr += zr[k] * cf - zi[k] * sf;
        oi  += zi[k] * cf + zr[k] * sf;
      }
      sre[base + h * 11 * CH] = orr; sim[base + h * 11 * CH] = oi;
    }
  }
  __syncthreads();

  // pass 4: inverse 11-pt DFT over w
  for (int col = t; col < 5 * 9 * CH; col += 256) {
    int kd = col / (9 * CH), r = col % (9 * CH), h = r / CH, c = r % CH;
    int base = (kd * 99 + h * 11) * CH + c;
    float xr[11], xi[11];
#pragma unroll
    for (int w = 0; w < 11; w++) { xr[w] = sre[base + w * CH]; xi[w] = sim[base + w * CH]; }
#pragma unroll
    for (int k = 0; k < 11; k++) {
      float yr = 0.f, yi = 0.f;
#pragma unroll
      for (int w = 0; w < 11; w++) {
        int j = (k * w) % 11; float cf = KC11[j], sf = KS11[j];
        yr += xr[w] * cf - xi[w] * sf;
        yi += xi[w] * cf + xr[w] * sf;
      }
      sre[base + k * CH] = yr; sim[base + k * CH] = yi;
    }
  }
  __syncthreads();

  // pass 5: d-irfft (5 -> 9), ortho scale, write y
  for (int col = t; col < 99 * CH; col += 256) {
    int pos = col / CH, c = col % CH;
    int cg = c0 + c;
    if (cg >= 900) continue;
    float Xr[5], Xi[5];
#pragma unroll
    for (int k = 0; k < 5; k++) { Xr[k] = sre[(k * 99 + pos) * CH + c]; Xi[k] = sim[(k * 99 + pos) * CH + c]; }
#pragma unroll
    for (int d = 0; d < 9; d++) {
      float acc = Xr[0];
#pragma unroll
      for (int k = 1; k < 5; k++) { int j = (k * d) % 9; acc += 2.f * (Xr[k] * KC9[j] - Xi[k] * KS9[j]); }
      y[((size_t)b * 891 + pos * 9 + d) * 900 + cg] = acc * (1.f / 891.f);
    }
  }
}

// ---------------- LN2 + bf16 emit: wave per token ----------------
__global__ __launch_bounds__(256) void k_ln2(const float* __restrict__ y, u16* __restrict__ yn) {
  int tok = blockIdx.x * 4 + (threadIdx.x >> 6);
  int l = threadIdx.x & 63;
  const float* row = y + (size_t)tok * 900;
  float v[15];
  float s1 = 0.f, s2 = 0.f;
#pragma unroll
  for (int j = 0; j < 15; j++) {
    int c = l + j * 64;
    float a = (c < 900) ? row[c] : 0.f;
    v[j] = a; s1 += a; s2 += a * a;
  }
#pragma unroll
  for (int off = 32; off; off >>= 1) { s1 += __shfl_xor(s1, off, 64); s2 += __shfl_xor(s2, off, 64); }
  float m = s1 * (1.f / 900.f);
  float var = s2 * (1.f / 900.f) - m * m;
  float rs = rsqrtf(var + LN_EPS);
  u16* orow = yn + (size_t)tok * 928;
#pragma unroll
  for (int j = 0; j < 15; j++) {
    int c = l + j * 64;
    if (c < 900) orow[c] = f2bf((v[j] - m) * rs);
    else if (c < 928) orow[c] = 0;
  }
}

// ---------------- bf16 MFMA GEMM, C = A(MxK) . B(NxK)^T, 2-stage pipelined ----------------
typedef __attribute__((address_space(1))) void gvoid;
typedef __attribute__((address_space(3))) void svoid;

__device__ __forceinline__ void stage16(const u16* g, u16* lbase) {
  __builtin_amdgcn_global_load_lds((gvoid*)(void*)g, (svoid*)lbase, 16, 0, 0);
}

// stage one 128x32 A-tile + 128x32 B-tile: 4 global_load_lds per thread (A,B,A,B).
// T2 swizzle (rule #21): LDS chunk p of row r holds GLOBAL k-chunk p ^ ((r>>1)&3).
__device__ __forceinline__ void stage_tile(const u16* __restrict__ A, const u16* __restrict__ B,
                                           int m0, int n0, int M, int N, int ldk, int k0,
                                           u16* As, u16* Bs, int w, int l) {
  int arow = (w << 4) + (l >> 2);
  int koff = k0 + (((l & 3) ^ ((l >> 3) & 3)) << 3);
#pragma unroll
  for (int j = 0; j < 2; j++) {
    int r = (j << 6) + arow;
    int gm = m0 + r; gm = gm < M ? gm : M - 1;
    stage16(A + (size_t)gm * ldk + koff, &As[((j << 6) + (w << 4)) * 32]);
    int gn = n0 + r; gn = gn < N ? gn : N - 1;
    stage16(B + (size_t)gn * ldk + koff, &Bs[((j << 6) + (w << 4)) * 32]);
  }
}

// EPI: 0 = bf16 store + bias (G1)   1 = bf16 store gelu(.+bias) (G2)
//      2 = bf16 store plain (G3)    3 = fp32 out = . + bias + x (G4)
template <int EPI>
__global__ __launch_bounds__(256, 2) void k_gemm(
    const u16* __restrict__ A, const u16* __restrict__ B,
    int M, int N, int Kt, int ldk, int NT,
    u16* __restrict__ Ob, int ldo, int Nstore,
    const float* __restrict__ bias,
    const float* __restrict__ Xres, float* __restrict__ Of) {
  __shared__ u16 As[2][128 * 32];
  __shared__ u16 Bs[2][128 * 32];
  int t = threadIdx.x, w = t >> 6, l = t & 63;

  // T1: XCD-chunked bijective block mapping (m204). Dispatch round-robins
  // blockIdx across the 8 XCDs; remap so each XCD owns a CONTIGUOUS range of
  // the mt-major enumeration -> all N-tiles of an M-tile run on one XCD and
  // the A panel stays in that XCD's L2 (kills the ~8x cross-XCD A re-fetch).
  int nblk = gridDim.x;
  int xcd = blockIdx.x & 7, idx = blockIdx.x >> 3;
  int q = nblk >> 3, r8 = nblk & 7;
  int lin = (xcd < r8 ? xcd * (q + 1) : r8 * (q + 1) + (xcd - r8) * q) + idx;
  int mt = lin / NT, nt = lin % NT;

  int m0 = mt * 128, n0 = nt * 128;
  int wm = (w >> 1) << 6, wn = (w & 1) << 6;
  int fr = l & 15, fq = l >> 4;
  // read-side inverse of the stage swizzle: chunk = fq ^ ((row>>1)&3)
  int rsw = ((fq ^ ((fr >> 1) & 3)) << 3);

  f32x4 acc[4][4];
  f32x4 zero = {0.f, 0.f, 0.f, 0.f};
#pragma unroll
  for (int i = 0; i < 4; i++)
#pragma unroll
    for (int j = 0; j < 4; j++) acc[i][j] = zero;

  // prologue: tiles 0 and 1 in flight
  stage_tile(A, B, m0, n0, M, N, ldk, 0, As[0], Bs[0], w, l);
  if (Kt > 1) stage_tile(A, B, m0, n0, M, N, ldk, 32, As[1], Bs[1], w, l);

  for (int kt = 0; kt < Kt; ++kt) {
    // drain ONLY tile kt's 4 loads (tile kt+1's 4 stay in flight), then barrier.
    if (kt + 1 < Kt) asm volatile("s_waitcnt vmcnt(4)\n\ts_barrier" ::: "memory");
    else             asm volatile("s_waitcnt vmcnt(0)\n\ts_barrier" ::: "memory");

    const u16* as = As[kt & 1];
    const u16* bs = Bs[kt & 1];
    bf16x8 af[4], bfr[4];
#pragma unroll
    for (int i = 0; i < 4; i++) af[i] = *(const bf16x8*)&as[(wm + (i << 4) + fr) * 32 + rsw];
#pragma unroll
    for (int i = 0; i < 4; i++) bfr[i] = *(const bf16x8*)&bs[(wn + (i << 4) + fr) * 32 + rsw];
#pragma unroll
    for (int i = 0; i < 4; i++)
#pragma unroll
      for (int j = 0; j < 4; j++)
        acc[i][j] = __builtin_amdgcn_mfma_f32_16x16x32_bf16(af[i], bfr[j], acc[i][j], 0, 0, 0);

    // all waves done reading buf[kt&1] before restaging into it
    asm volatile("s_barrier" ::: "memory");
    if (kt + 2 < Kt)
      stage_tile(A, B, m0, n0, M, N, ldk, (kt + 2) * 32, As[kt & 1], Bs[kt & 1], w, l);
  }

#pragma unroll
  for (int j = 0; j < 4; j++) {
    int gn = n0 + wn + (j << 4) + fr;
    float bv = 0.f;
    if (EPI != 2) bv = (gn < Nstore) ? bias[gn] : 0.f;
#pragma unroll
    for (int i = 0; i < 4; i++) {
#pragma unroll
      for (int r = 0; r < 4; r++) {
        int gm = m0 + wm + (i << 4) + (fq << 2) + r;
        if (gm < M) {
          float val = acc[i][j][r] + bv;
          if (EPI == 1) val = gelu_f(val);
          if (EPI == 3) {
            if (gn < Nstore) Of[(size_t)gm * Nstore + gn] = val + Xres[(size_t)gm * Nstore + gn];
          } else {
            if (gn < ldo) Ob[(size_t)gm * ldo + gn] = (gn < Nstore) ? f2bf(val) : (u16)0;
          }
        }
      }
    }
  }
}

// ---------------- launch ----------------
extern "C" void kernel_launch(void* const* d_in, const int* in_sizes, int n_in,
                              void* d_out, int out_size, void* d_ws, size_t ws_size,
                              hipStream_t stream) {
  const float* x   = (const float*)d_in[0];
  const float* cw  = (const float*)d_in[1];
  const float* g1  = (const float*)d_in[2];
  const float* b1  = (const float*)d_in[3];
  const float* g2  = (const float*)d_in[4];
  const float* b2  = (const float*)d_in[5];
  const float* u1w = (const float*)d_in[6];
  const float* v1w = (const float*)d_in[7];
  const float* v1b = (const float*)d_in[8];
  const float* u2w = (const float*)d_in[9];
  const float* v2w = (const float*)d_in[10];
  const float* v2b = (const float*)d_in[11];

  char* ws = (char*)d_ws;
  float* y   = (float*)ws;                                   // 205,286,400 B
  u16*   t2  = (u16*)ws;                                     // reuse: 57024*1824*2 = 208,023,552 B
  u16*   t3  = (u16*)(ws + 228096000);                       // 58,392,576 B
  u16*   u1g = (u16*)(ws + 286488576);                       // 450*928*2
  u16*   v1c = (u16*)(ws + 287323776);                       // 1800*512*2
  u16*   u2c = (u16*)(ws + 289166976);                       // 450*1824*2
  u16*   v2c = (u16*)(ws + 290808576);                       // 900*512*2
  float* b1r = (float*)(ws + 291730176);                     // 450*4

  u16*    yn    = (u16*)d_out;                               // 57024*928*2 = 105,836,544 B
  u16*    t1    = (u16*)((char*)d_out + 105836544);          // 57024*512*2 = 58,392,576 B
  float2* stats = (float2*)((char*)d_out + 164229120);       // 57024*8 = 456,192 B
  float*  outF  = (float*)d_out;

  // weight prep (tiny)
  k_cvt<<<1632, 256, 0, stream>>>(u1w, u1g, 450, 900, 928, g2);
  k_cvt<<<3600, 256, 0, stream>>>(v1w, v1c, 1800, 450, 512, nullptr);
  k_cvt<<<3207, 256, 0, stream>>>(u2w, u2c, 450, 1800, 1824, nullptr);
  k_cvt<<<1800, 256, 0, stream>>>(v2w, v2c, 900, 450, 512, nullptr);
  k_bias1<<<2, 256, 0, stream>>>(u1w, b2, b1r);

  // spectral filter (fused)
  k_stats1<<<14256, 256, 0, stream>>>(x, stats);
  k_spectral<<<64 * 57, 256, 0, stream>>>(x, stats, g1, b1, cw, y);
  k_ln2<<<14256, 256, 0, stream>>>(y, yn);

  // MLP GEMMs: M=57024 (446 tiles of 128)
  k_gemm<0><<<446 * 4,  256, 0, stream>>>(yn, u1g, 57024, 450,  29, 928,  4,  t1, 512, 450, b1r, nullptr, nullptr);
  k_gemm<1><<<446 * 15, 256, 0, stream>>>(t1, v1c, 57024, 1800, 16, 512,  15, t2, 1824, 1800, v1b, nullptr, nullptr);
  k_gemm<2><<<446 * 4,  256, 0, stream>>>(t2, u2c, 57024, 450,  57, 1824, 4,  t3, 512, 450, nullptr, nullptr, nullptr);
  k_gemm<3><<<446 * 8,  256, 0, stream>>>(t3, v2c, 57024, 900,  16, 512,  8,  nullptr, 0, 900, v2b, x, outF);
}